// Round 6
// baseline (64.988 us; speedup 1.0000x reference)
//
#include <hip/hip_runtime.h>

typedef unsigned long long u64;
typedef unsigned int u32;

#define NB 64      // graphs
#define NN 128     // nodes per graph
#define NITER 5
#define NGEN 6     // initial labels + 5 WL iterations
#define SALT 0xD1B54A32D192ED03ULL
#define NBLK 496   // triangular 2x2 tiles: TI in [1,32), TJ < TI

__device__ __forceinline__ u64 mix64(u64 x) {
    u64 z = x + 0x9E3779B97F4A7C15ULL;
    z = (z ^ (z >> 30)) * 0xBF58476D1CE4E5B9ULL;
    z = (z ^ (z >> 27)) * 0x94D049BB133111EBULL;
    return z ^ (z >> 31);
}

__device__ __forceinline__ void tab_insert(u64* keys, u32* cnts, u64 key) {
    u32 s = (u32)key & 255u;
    for (;;) {
        u64 old = atomicCAS((unsigned long long*)&keys[s], 0ULL, key);
        if (old == 0ULL || old == key) { atomicAdd(&cnts[s], 1u); return; }
        s = (s + 1) & 255u;
    }
}

__device__ __forceinline__ u32 tab_lookup(const u64* keys, const u32* cnts, u64 key) {
    u32 s = (u32)key & 255u;
    for (;;) {
        const u64 k = keys[s];
        if (k == key) return cnts[s];
        if (k == 0ULL) return 0u;
        s = (s + 1) & 255u;
    }
}

// One block per 2x2 tile of graph pairs. Block is fully self-contained:
// packs adjacency (L2-resident, redundant across blocks), runs WL for its 4
// graphs in parallel (128 threads each: thread = one node of one graph),
// builds a per-generation 256-slot hash table per graph (ping-ponged), probes
// cross-tables for pair counts + own table for the diagonal norm, and writes
// normalized outputs. Blocks with TJ==TI-1 also own diagonal tile TI (pair
// (2TI+1,2TI) + the two 1.0 diagonal entries); block (1,0) additionally owns
// diagonal tile 0.
__global__ __launch_bounds__(512, 4) void wl_fused(const float* __restrict__ adj,
                                                   const int* __restrict__ labels,
                                                   float* __restrict__ out) {
    const int p = blockIdx.x;
    int TI = (int)((1.0f + sqrtf(1.0f + 8.0f * (float)p)) * 0.5f);
    while (TI * (TI - 1) / 2 > p) --TI;
    while ((TI + 1) * TI / 2 <= p) ++TI;
    const int TJ = p - TI * (TI - 1) / 2;   // 0 <= TJ < TI

    const int t    = threadIdx.x;
    const int lg   = t >> 7;    // local graph 0..3 = {I0, I1, J0, J1}
    const int u    = t & 127;   // node owned by this thread
    const int lane = t & 63;
    const int wv   = t >> 6;    // wave 0..7 (waves 2k,2k+1 belong to lg k)

    const int gb = (lg < 2) ? (2 * TI + lg) : (2 * TJ + (lg - 2));

    __shared__ u64 bitsA[4][NN];   // adjacency mask, low 64 cols
    __shared__ u64 bitsB[4][NN];   // high 64 cols
    __shared__ u64 gsh[4][NN];     // mix(h ^ SALT) per node (WL neighbor feed)
    __shared__ u64 keys[4][256];   // per-graph per-gen hash table (reused)
    __shared__ u32 cnts[4][256];
    __shared__ u32 red[8][4];      // per-wave reduction partials

    // ---- pack adjacency for my local graph (2 waves x 64 rows, coalesced) ----
    {
        const float* abase = adj + (size_t)gb * NN * NN;
        const int rbase = (wv & 1) << 6;
        #pragma unroll 4
        for (int k = 0; k < 64; ++k) {
            const int row = rbase + k;
            const float* arow = abase + row * NN;
            u64 m0 = __ballot(arow[lane] > 0.5f);
            u64 m1 = __ballot(arow[64 + lane] > 0.5f);
            if (lane == 0) { bitsA[lg][row] = m0; bitsB[lg][row] = m1; }
        }
    }

    // ---- generation-0 label (pure register state) ----
    u64 h = mix64((u64)(unsigned)labels[gb * NN + u]);

    u32 cJ0 = 0, cJ1 = 0, cX = 0, dAcc = 0;

    for (int gen = 0; gen < NGEN; ++gen) {
        // phase 1: zero my graph's table; publish neighbor-feed value
        keys[lg][u] = 0ULL;  keys[lg][u + 128] = 0ULL;
        cnts[lg][u] = 0u;    cnts[lg][u + 128] = 0u;
        gsh[lg][u] = mix64(h ^ SALT);
        __syncthreads();

        // phase 2: insert own label into own graph's table
        tab_insert(keys[lg], cnts[lg], h);
        __syncthreads();

        // phase 3: probes + diagonal accumulation + WL step (in registers)
        if (lg < 2) {
            cJ0 += tab_lookup(keys[2], cnts[2], h);
            cJ1 += tab_lookup(keys[3], cnts[3], h);
        }
        if (lg == 1) cX += tab_lookup(keys[0], cnts[0], h);  // pair (I1, I0)
        if (lg == 3) cX += tab_lookup(keys[2], cnts[2], h);  // pair (J1, J0)
        {
            const u32 c1 = cnts[lg][u];
            const u32 c2 = cnts[lg][u + 128];
            dAcc += c1 * c1 + c2 * c2;
        }
        u64 hn = h;
        if (gen < NITER) {
            const u64* gp = gsh[lg];
            u64 s = 0;
            u64 m = bitsA[lg][u];
            while (m) { int j = __builtin_ctzll(m); m &= m - 1; s += gp[j]; }
            m = bitsB[lg][u];
            while (m) { int j = __builtin_ctzll(m); m &= m - 1; s += gp[64 + j]; }
            hn = mix64(mix64(h) + s);
        }
        __syncthreads();   // table reads + gsh reads done before next overwrite
        h = hn;
    }

    // ---- reduce (cJ0, cJ1, cX, dAcc) over each wave, then combine ----
    {
        u32 r0 = cJ0, r1 = cJ1, r2 = cX, r3 = dAcc;
        #pragma unroll
        for (int off = 32; off > 0; off >>= 1) {
            r0 += __shfl_down(r0, off);
            r1 += __shfl_down(r1, off);
            r2 += __shfl_down(r2, off);
            r3 += __shfl_down(r3, off);
        }
        if (lane == 0) { red[wv][0] = r0; red[wv][1] = r1; red[wv][2] = r2; red[wv][3] = r3; }
    }
    __syncthreads();

    if (t == 0) {
        u32 Q[4][4];
        #pragma unroll
        for (int g = 0; g < 4; ++g)
            #pragma unroll
            for (int q = 0; q < 4; ++q)
                Q[g][q] = red[2 * g][q] + red[2 * g + 1][q];

        const float sD0 = sqrtf((float)Q[0][3]);  // Kdiag(I0)
        const float sD1 = sqrtf((float)Q[1][3]);  // Kdiag(I1)
        const float sD2 = sqrtf((float)Q[2][3]);  // Kdiag(J0)
        const float sD3 = sqrtf((float)Q[3][3]);  // Kdiag(J1)

        const int bI0 = 2 * TI, bI1 = 2 * TI + 1;
        const int bJ0 = 2 * TJ, bJ1 = 2 * TJ + 1;

        const float v00 = (float)Q[0][0] / (sD0 * sD2);
        const float v01 = (float)Q[0][1] / (sD0 * sD3);
        const float v10 = (float)Q[1][0] / (sD1 * sD2);
        const float v11 = (float)Q[1][1] / (sD1 * sD3);
        out[bI0 * NB + bJ0] = v00;  out[bJ0 * NB + bI0] = v00;
        out[bI0 * NB + bJ1] = v01;  out[bJ1 * NB + bI0] = v01;
        out[bI1 * NB + bJ0] = v10;  out[bJ0 * NB + bI1] = v10;
        out[bI1 * NB + bJ1] = v11;  out[bJ1 * NB + bI1] = v11;

        if (TJ == TI - 1) {  // own diagonal tile TI
            const float vII = (float)Q[1][2] / (sD1 * sD0);
            out[bI1 * NB + bI0] = vII;  out[bI0 * NB + bI1] = vII;
            out[bI0 * NB + bI0] = 1.0f; out[bI1 * NB + bI1] = 1.0f;
        }
        if (TI == 1 && TJ == 0) {  // own diagonal tile 0 (graphs 0,1)
            const float vJJ = (float)Q[3][2] / (sD3 * sD2);
            out[bJ1 * NB + bJ0] = vJJ;  out[bJ0 * NB + bJ1] = vJJ;
            out[bJ0 * NB + bJ0] = 1.0f; out[bJ1 * NB + bJ1] = 1.0f;
        }
    }
}

extern "C" void kernel_launch(void* const* d_in, const int* in_sizes, int n_in,
                              void* d_out, int out_size, void* d_ws, size_t ws_size,
                              hipStream_t stream) {
    const float* adj   = (const float*)d_in[0];   // [64,128,128] fp32 (0/1)
    const int*  labels = (const int*)d_in[1];     // [64,128] int32
    float* out = (float*)d_out;                   // [64,64] fp32

    wl_fused<<<NBLK, 512, 0, stream>>>(adj, labels, out);
}

// Round 7
// 27.963 us; speedup vs baseline: 2.3241x; 2.3241x over previous
//
#include <hip/hip_runtime.h>

typedef unsigned long long u64;
typedef unsigned int u32;

#define NB 64      // graphs
#define NN 128     // nodes per graph
#define NITER 5
#define NGEN 6     // initial labels + 5 WL iterations
#define SALT 0xD1B54A32D192ED03ULL
#define NPAIR_OFF (NB*(NB-1)/2)  // 2016 strict lower-triangular pairs
#define TSLOTS 256

__device__ __forceinline__ u64 mix64(u64 x) {
    u64 z = x + 0x9E3779B97F4A7C15ULL;
    z = (z ^ (z >> 30)) * 0xBF58476D1CE4E5B9ULL;
    z = (z ^ (z >> 27)) * 0x94D049BB133111EBULL;
    return z ^ (z >> 31);
}

// K1: serial WL chain — the ONLY per-graph-serial stage, kept minimal.
// One block per graph, 512 threads = 4 quarter-threads per node.
// Quarter-thread (u, q) holds a 32-bit register mask of row u, cols 32q..32q+31
// (built from 8 pipelined float4 loads — no ballot chains, no LDS mask store).
// Per WL iteration: 2 barriers, short ctz loop (~4 avg neighbors/quarter) with
// pipelined LDS reads. h lives only in q==0 threads' registers.
__global__ __launch_bounds__(512) void wl_iter(const float* __restrict__ adj,
                                               const int* __restrict__ labels,
                                               u64* __restrict__ hgen,
                                               u32* __restrict__ KdiagU,
                                               float* __restrict__ out) {
    const int b = blockIdx.x;
    const int t = threadIdx.x;
    const int u = t & 127;   // node
    const int q = t >> 7;    // quarter 0..3

    __shared__ u64 gsh[NN];
    __shared__ u64 psum[3][NN];  // partial sums from q=1..3

    // build register adjacency quarter-mask
    const float* rowp = adj + ((size_t)b * NN + u) * NN + q * 32;
    u32 m = 0;
    #pragma unroll
    for (int k = 0; k < 8; ++k) {
        const float4 v = *(const float4*)(rowp + 4 * k);
        m |= (v.x > 0.5f ? 1u : 0u) << (4 * k);
        m |= (v.y > 0.5f ? 1u : 0u) << (4 * k + 1);
        m |= (v.z > 0.5f ? 1u : 0u) << (4 * k + 2);
        m |= (v.w > 0.5f ? 1u : 0u) << (4 * k + 3);
    }

    u64 h = 0;
    if (q == 0) {
        h = mix64((u64)(u32)labels[b * NN + u]);
        hgen[((size_t)b * NGEN) * NN + u] = h;     // generation 0
        if (u == 0) out[b * NB + b] = 1.0f;        // output diagonal
        if (u == 1) KdiagU[b] = 0u;                // zero diag accumulator for K2
    }

    for (int it = 0; it < NITER; ++it) {
        if (q == 0) gsh[u] = mix64(h ^ SALT);
        __syncthreads();
        u64 s = 0;
        {
            u32 mm = m;
            const u64* gp = gsh + q * 32;
            while (mm) { int j = __builtin_ctz(mm); mm &= mm - 1; s += gp[j]; }
        }
        if (q) psum[q - 1][u] = s;
        __syncthreads();
        if (q == 0) {
            h = mix64(mix64(h) + s + psum[0][u] + psum[1][u] + psum[2][u]);
            hgen[((size_t)b * NGEN + (it + 1)) * NN + u] = h;
        }
        // next iteration's gsh write is ordered after this barrier; all reads of
        // the current gsh completed before it.
    }
}

// K2: per-(graph,generation) hash table build — 384 independent blocks.
// 256-slot open addressing, keys are splitmix64 outputs (low 8 bits = hash).
// Exports SoA keys/counts and atomically accumulates Kdiag[b] = sum cnt^2.
__global__ __launch_bounds__(128) void wl_tables(const u64* __restrict__ hgen,
                                                 u64* __restrict__ keysg,
                                                 u32* __restrict__ cntsg,
                                                 u32* __restrict__ KdiagU) {
    const int bg = blockIdx.x;   // b*NGEN + gen
    const int t = threadIdx.x;

    __shared__ u64 keys[TSLOTS];
    __shared__ u32 cnts[TSLOTS];
    keys[t] = 0ULL; keys[t + 128] = 0ULL;
    cnts[t] = 0u;   cnts[t + 128] = 0u;
    __syncthreads();

    const u64 h = hgen[(size_t)bg * NN + t];
    u32 s = (u32)h & (TSLOTS - 1);
    for (;;) {
        u64 old = atomicCAS((unsigned long long*)&keys[s], 0ULL, h);
        if (old == 0ULL || old == h) { atomicAdd(&cnts[s], 1u); break; }
        s = (s + 1) & (TSLOTS - 1);
    }
    __syncthreads();

    u32 acc;
    {
        const u64 k0 = keys[t], k1 = keys[t + 128];
        const u32 c0 = cnts[t], c1 = cnts[t + 128];
        keysg[(size_t)bg * TSLOTS + t]       = k0;
        keysg[(size_t)bg * TSLOTS + t + 128] = k1;
        cntsg[(size_t)bg * TSLOTS + t]       = c0;
        cntsg[(size_t)bg * TSLOTS + t + 128] = c1;
        acc = c0 * c0 + c1 * c1;
    }
    #pragma unroll
    for (int off = 32; off > 0; off >>= 1) acc += __shfl_down(acc, off);
    __shared__ u32 part[2];
    if ((t & 63) == 0) part[t >> 6] = acc;
    __syncthreads();
    if (t == 0) atomicAdd(&KdiagU[bg / NGEN], part[0] + part[1]);
}

// K3: one block per strict lower pair (b1>b2), 256 threads.
// Stage b2's 6 tables (SoA: 12KB keys + 6KB counts), probe with b1's 768
// labels (3/thread, coalesced), normalize with Kdiag, write both triangles.
__global__ __launch_bounds__(256) void wl_pairs(const u64* __restrict__ hgen,
                                                const u64* __restrict__ keysg,
                                                const u32* __restrict__ cntsg,
                                                const u32* __restrict__ KdiagU,
                                                float* __restrict__ out) {
    const int p = blockIdx.x;
    int b1 = (int)((1.0f + sqrtf(1.0f + 8.0f * (float)p)) * 0.5f);
    while (b1 * (b1 - 1) / 2 > p) --b1;
    while ((b1 + 1) * b1 / 2 <= p) ++b1;
    const int b2 = p - b1 * (b1 - 1) / 2;

    const int t = threadIdx.x;
    __shared__ u64 keys[NGEN * TSLOTS];  // 12 KiB
    __shared__ u32 cnts[NGEN * TSLOTS];  // 6 KiB

    {   // stage keys: 768 x ulonglong2 over 256 threads
        const ulonglong2* src = (const ulonglong2*)(keysg + (size_t)b2 * NGEN * TSLOTS);
        ulonglong2* dst = (ulonglong2*)keys;
        #pragma unroll
        for (int k = 0; k < 3; ++k) dst[t + 256 * k] = src[t + 256 * k];
    }
    {   // stage counts: 384 x uint4 over 256 threads
        const uint4* src = (const uint4*)(cntsg + (size_t)b2 * NGEN * TSLOTS);
        uint4* dst = (uint4*)cnts;
        #pragma unroll
        for (int k = 0; k < 2; ++k) {
            const int idx = t + 256 * k;
            if (idx < 384) dst[idx] = src[idx];
        }
    }
    __syncthreads();

    u32 c = 0;
    const u64* abase = hgen + (size_t)b1 * NGEN * NN;
    #pragma unroll
    for (int k = 0; k < 3; ++k) {
        const int idx = t + 256 * k;        // 0..767 -> gen = idx>>7
        const u64 a = abase[idx];
        const int base = (idx >> 7) * TSLOTS;
        u32 s = (u32)a & (TSLOTS - 1);
        for (;;) {
            const u64 kk = keys[base + s];
            if (kk == a) { c += cnts[base + s]; break; }
            if (kk == 0ULL) break;
            s = (s + 1) & (TSLOTS - 1);
        }
    }

    #pragma unroll
    for (int off = 32; off > 0; off >>= 1) c += __shfl_down(c, off);
    __shared__ u32 part[4];
    if ((t & 63) == 0) part[t >> 6] = c;
    __syncthreads();
    if (t == 0) {
        const float v = (float)(part[0] + part[1] + part[2] + part[3])
                      / (sqrtf((float)KdiagU[b1]) * sqrtf((float)KdiagU[b2]));
        out[b1 * NB + b2] = v;
        out[b2 * NB + b1] = v;
    }
}

extern "C" void kernel_launch(void* const* d_in, const int* in_sizes, int n_in,
                              void* d_out, int out_size, void* d_ws, size_t ws_size,
                              hipStream_t stream) {
    const float* adj   = (const float*)d_in[0];   // [64,128,128] fp32 (0/1)
    const int*  labels = (const int*)d_in[1];     // [64,128] int32
    float* out = (float*)d_out;                   // [64,64] fp32

    char* ws = (char*)d_ws;
    u64* hgen  = (u64*)ws;                         // 64*6*128*8  = 384 KiB
    u64* keysg = (u64*)(ws + 512 * 1024);          // 384*256*8   = 768 KiB
    u32* cntsg = (u32*)(ws + 1536 * 1024);         // 384*256*4   = 384 KiB
    u32* KdiagU = (u32*)(ws + 2048 * 1024);        // 256 B

    wl_iter  <<<NB, 512, 0, stream>>>(adj, labels, hgen, KdiagU, out);
    wl_tables<<<NB * NGEN, 128, 0, stream>>>(hgen, keysg, cntsg, KdiagU);
    wl_pairs <<<NPAIR_OFF, 256, 0, stream>>>(hgen, keysg, cntsg, KdiagU, out);
}